// Round 1
// baseline (163.896 us; speedup 1.0000x reference)
//
#include <hip/hip_runtime.h>
#include <math.h>

#define Bn 256
#define Dm 256
#define Hm 512
#define Em 64
#define NL 1024
#define TOPK 10

// ---------------- dense layer: Y[b,j] = act(sum_i X[b,i] * W[i,j] + bias[j]) ----------------
template<int IN, int OUT>
__global__ void dense_relu_kernel(const float* __restrict__ X, const float* __restrict__ W,
                                  const float* __restrict__ bias, float* __restrict__ Y) {
    __shared__ float sx[IN];
    const int b = blockIdx.x;
    const int j = threadIdx.x;  // OUT threads
    for (int i = threadIdx.x; i < IN; i += OUT) sx[i] = X[b * IN + i];
    __syncthreads();
    float acc = bias[j];
    #pragma unroll 8
    for (int i = 0; i < IN; ++i) acc = fmaf(sx[i], W[i * OUT + j], acc);
    Y[b * OUT + j] = fmaxf(acc, 0.f);
}

// ---------------- root layer 3 + argmax + log-softmax at argmax ----------------
__global__ void root3_kernel(const float* __restrict__ H2, const float* __restrict__ W,
                             const float* __restrict__ bias, int* __restrict__ idx_out,
                             float* __restrict__ rlp_out) {
    __shared__ float sx[Hm];
    const int b = blockIdx.x;
    const int j = threadIdx.x;  // 64 threads (one wave)
    for (int i = j; i < Hm; i += 64) sx[i] = H2[b * Hm + i];
    __syncthreads();
    float acc = bias[j];
    #pragma unroll 8
    for (int i = 0; i < Hm; ++i) acc = fmaf(sx[i], W[i * Em + j], acc);
    // wave argmax (tie -> smaller index, matching jnp.argmax)
    float v = acc; int bi = j;
    #pragma unroll
    for (int off = 32; off; off >>= 1) {
        float ov = __shfl_xor(v, off);
        int   oi = __shfl_xor(bi, off);
        if (ov > v || (ov == v && oi < bi)) { v = ov; bi = oi; }
    }
    // v = max logit (all lanes agree)
    float s = expf(acc - v);
    #pragma unroll
    for (int off = 32; off; off >>= 1) s += __shfl_xor(s, off);
    if (j == 0) {
        idx_out[b] = bi;
        rlp_out[b] = -logf(s);  // log_softmax at the argmax position
    }
}

// ---------------- expert dense layer (per-sample routed weights) ----------------
template<int IN, int OUT>
__global__ void expert_dense_kernel(const float* __restrict__ X, const float* __restrict__ W,
                                    const float* __restrict__ bias, const int* __restrict__ idx,
                                    float* __restrict__ Y) {
    __shared__ float sx[IN];
    const int b = blockIdx.x;
    const int e = idx[b];
    const int j = threadIdx.x;  // OUT threads
    for (int i = threadIdx.x; i < IN; i += OUT) sx[i] = X[b * IN + i];
    __syncthreads();
    const float* We = W + (size_t)e * IN * OUT;
    float acc = bias[e * OUT + j];
    #pragma unroll 8
    for (int i = 0; i < IN; ++i) acc = fmaf(sx[i], We[i * OUT + j], acc);
    Y[b * OUT + j] = fmaxf(acc, 0.f);
}

// ---------------- expert layer 3 + log-softmax + top-11 + filter + write outputs ----------------
__global__ void expert3_topk_kernel(const float* __restrict__ H2e, const float* __restrict__ W3,
                                    const float* __restrict__ b3, const int* __restrict__ idx,
                                    const float* __restrict__ rlp, float* __restrict__ out) {
    __shared__ float sx[Hm];
    __shared__ float sl[NL];
    __shared__ float redA[8];
    __shared__ float redB[8];
    __shared__ float bcast[2];
    const int b = blockIdx.x;
    const int e = idx[b];
    const int tid = threadIdx.x;  // 512 threads
    for (int i = tid; i < Hm; i += 512) sx[i] = H2e[b * Hm + i];
    __syncthreads();

    const float* We = W3 + (size_t)e * Hm * NL;
    float acc0 = b3[e * NL + tid];
    float acc1 = b3[e * NL + tid + 512];
    #pragma unroll 4
    for (int i = 0; i < Hm; ++i) {
        const float xv = sx[i];
        acc0 = fmaf(xv, We[i * NL + tid], acc0);
        acc1 = fmaf(xv, We[i * NL + tid + 512], acc1);
    }
    sl[tid]       = acc0;
    sl[tid + 512] = acc1;

    // block max
    float m = fmaxf(acc0, acc1);
    #pragma unroll
    for (int off = 32; off; off >>= 1) m = fmaxf(m, __shfl_xor(m, off));
    const int wid = tid >> 6;
    if ((tid & 63) == 0) redA[wid] = m;
    __syncthreads();
    if (tid == 0) {
        float mm = redA[0];
        #pragma unroll
        for (int w = 1; w < 8; ++w) mm = fmaxf(mm, redA[w]);
        bcast[0] = mm;
    }
    __syncthreads();
    m = bcast[0];

    // block sum of exp
    float s = expf(acc0 - m) + expf(acc1 - m);
    #pragma unroll
    for (int off = 32; off; off >>= 1) s += __shfl_xor(s, off);
    if ((tid & 63) == 0) redB[wid] = s;
    __syncthreads();
    if (tid == 0) {
        float ss = 0.f;
        #pragma unroll
        for (int w = 0; w < 8; ++w) ss += redB[w];
        bcast[1] = m + logf(ss);  // logZ
    }
    __syncthreads();
    const float logZ = bcast[1];

    // top-11 selection by wave 0 (16 candidates per lane, held in registers)
    if (tid < 64) {
        float vals[16];
        #pragma unroll
        for (int q = 0; q < 16; ++q) vals[q] = sl[tid * 16 + q];
        float selv[11];
        int   seli[11];
        for (int t = 0; t < 11; ++t) {
            float v = -INFINITY; int bq = 0;
            #pragma unroll
            for (int q = 0; q < 16; ++q) {
                if (vals[q] > v) { v = vals[q]; bq = q; }  // first occurrence on ties
            }
            int gi = tid * 16 + bq;
            #pragma unroll
            for (int off = 32; off; off >>= 1) {
                float ov = __shfl_xor(v, off);
                int   oi = __shfl_xor(gi, off);
                if (ov > v || (ov == v && oi < gi)) { v = ov; gi = oi; }
            }
            selv[t] = v;
            seli[t] = gi;
            if ((gi >> 4) == tid) vals[gi & 15] = -INFINITY;  // owner removes winner
        }
        if (tid == 0) {
            const float rl = rlp[b];
            int cnt = 0;
            for (int t = 0; t < 11 && cnt < TOPK; ++t) {
                if (seli[t] == 0 && e == 0) continue;  // drop the (0,0) trajectory
                out[(b * TOPK + cnt) * 2 + 0] = (float)e;
                out[(b * TOPK + cnt) * 2 + 1] = (float)seli[t];
                out[Bn * TOPK * 2 + b * TOPK + cnt] = selv[t] - logZ + rl;
                ++cnt;
            }
        }
    }
}

extern "C" void kernel_launch(void* const* d_in, const int* in_sizes, int n_in,
                              void* d_out, int out_size, void* d_ws, size_t ws_size,
                              hipStream_t stream) {
    const float* state = (const float*)d_in[0];
    const float* rW1   = (const float*)d_in[1];
    const float* rb1   = (const float*)d_in[2];
    const float* rW2   = (const float*)d_in[3];
    const float* rb2   = (const float*)d_in[4];
    const float* rW3   = (const float*)d_in[5];
    const float* rb3   = (const float*)d_in[6];
    const float* eW1   = (const float*)d_in[7];
    const float* eb1   = (const float*)d_in[8];
    const float* eW2   = (const float*)d_in[9];
    const float* eb2   = (const float*)d_in[10];
    const float* eW3   = (const float*)d_in[11];
    const float* eb3   = (const float*)d_in[12];
    float* out = (float*)d_out;

    float* h1  = (float*)d_ws;          // B*H
    float* h2  = h1  + Bn * Hm;         // B*H
    float* eh1 = h2  + Bn * Hm;         // B*H
    float* eh2 = eh1 + Bn * Hm;         // B*H
    float* rlp = eh2 + Bn * Hm;         // B
    int*   idxp = (int*)(rlp + Bn);     // B

    dense_relu_kernel<Dm, Hm><<<Bn, Hm, 0, stream>>>(state, rW1, rb1, h1);
    dense_relu_kernel<Hm, Hm><<<Bn, Hm, 0, stream>>>(h1, rW2, rb2, h2);
    root3_kernel<<<Bn, 64, 0, stream>>>(h2, rW3, rb3, idxp, rlp);
    expert_dense_kernel<Dm, Hm><<<Bn, Hm, 0, stream>>>(state, eW1, eb1, idxp, eh1);
    expert_dense_kernel<Hm, Hm><<<Bn, Hm, 0, stream>>>(eh1, eW2, eb2, idxp, eh2);
    expert3_topk_kernel<<<Bn, Hm, 0, stream>>>(eh2, eW3, eb3, idxp, rlp, out);
}